// Round 5
// baseline (439.349 us; speedup 1.0000x reference)
//
#include <hip/hip_runtime.h>

// RegressionWisard predict (centrality='mean')
//   input:  [B=4096, E=8192] int32 bits
//   map:    [E] permutation int32 (identity in the benchmark)
//   counts: [N=512, 65536] int32
//   sums:   [N=512, 65536] float32
//   out:    [B] float32 = nan_to_num(sum(s where c>0) / sum(c where c>0))
//
// R7: R6 proved the table-stream design (FETCH 139MB < 256MB streamed: L3
// retains the tables) but was Little's-law starved: 8 waves/CU x 128B in
// flight. Fixes: (1) stream kernel serves hits with DIRECT global float2
// stores (dense permutation of a 32KB range -> L2 write-combines) killing
// the 32KB acc LDS -> 33KB LDS -> 4 blocks/CU, plus register double-buffer
// on the line sweep; (2) addr kernel: lane owns 4 neurons = 256B -> 16
// dwordx4 outstanding per wait (was 4); (3) final kernel grid 64 -> 256.

constexpr int BATCH   = 4096;
constexpr int ENTRY   = 8192;
constexpr int TUP     = 16;
constexpr int NEUR    = ENTRY / TUP;    // 512
constexpr int LINES   = 4096;           // 16-entry (64B) lines per table
constexpr int THREADS = 256;

typedef int v4i __attribute__((ext_vector_type(4)));
typedef unsigned int uint;

__device__ __forceinline__ int pack16(v4i b0, v4i b1, v4i b2, v4i b3) {
    // tuple bit 0 is the MSB of the address
    return ((b0.x & 1) << 15) | ((b0.y & 1) << 14)
         | ((b0.z & 1) << 13) | ((b0.w & 1) << 12)
         | ((b1.x & 1) << 11) | ((b1.y & 1) << 10)
         | ((b1.z & 1) <<  9) | ((b1.w & 1) <<  8)
         | ((b2.x & 1) <<  7) | ((b2.y & 1) <<  6)
         | ((b2.z & 1) <<  5) | ((b2.w & 1) <<  4)
         | ((b3.x & 1) <<  3) | ((b3.y & 1) <<  2)
         | ((b3.z & 1) <<  1) |  (b3.w & 1);
}

// 16-way register select via cndmask tree (static indices only; rule #20)
__device__ __forceinline__ int sel4(v4i v, int e01) {
    const int ab = (e01 & 1) ? v.y : v.x;
    const int cd = (e01 & 1) ? v.w : v.z;
    return (e01 & 2) ? cd : ab;
}
__device__ __forceinline__ int sel16(v4i v0, v4i v1, v4i v2, v4i v3, int e) {
    const int e2 = e & 3;
    const int a = sel4(v0, e2), b = sel4(v1, e2);
    const int c = sel4(v2, e2), d = sel4(v3, e2);
    const int ab = (e & 4) ? b : a;
    const int cd = (e & 4) ? d : c;
    return (e & 8) ? cd : ab;
}

// ---- Phase A: addr_t[s][n] --------------------------------------------------
// grid 1024 x 256: wave = one sample; lane owns 4 neurons = 256B contiguous
// input per macro-step -> 16 dwordx4 in flight per wave per wait.
__global__ __launch_bounds__(THREADS, 4) void wisard_addr(
    const int* __restrict__ input,
    const int* __restrict__ mapping,
    unsigned short* __restrict__ addr_t)   // [BATCH][NEUR]
{
    const int lane = threadIdx.x & 63;
    const int w    = threadIdx.x >> 6;
    const int s    = blockIdx.x * 4 + w;
    const int* row = input + (size_t)s * ENTRY;

    #pragma unroll
    for (int j = 0; j < 2; ++j) {                 // 2 macro-steps x 256 neurons
        const int nb = j * 256 + lane * 4;        // my 4 neurons: nb..nb+3
        int  m0s[4];
        bool cg [4];
        #pragma unroll
        for (int q = 0; q < 4; ++q) {
            const int* map_n = mapping + (nb + q) * TUP;
            const int m0 = map_n[0];
            bool contig = ((m0 & 3) == 0);
            #pragma unroll
            for (int t = 1; t < TUP; ++t) contig &= (map_n[t] == m0 + t);
            m0s[q] = m0; cg[q] = contig;
        }

        // issue ALL 16 loads before any consumption
        v4i buf[16];
        #pragma unroll
        for (int q = 0; q < 4; ++q) {
            if (cg[q]) {
                const v4i* p = reinterpret_cast<const v4i*>(row + m0s[q]);
                buf[q * 4 + 0] = __builtin_nontemporal_load(p);
                buf[q * 4 + 1] = __builtin_nontemporal_load(p + 1);
                buf[q * 4 + 2] = __builtin_nontemporal_load(p + 2);
                buf[q * 4 + 3] = __builtin_nontemporal_load(p + 3);
            } else {
                const int* map_n = mapping + (nb + q) * TUP;
                #pragma unroll
                for (int i = 0; i < 4; ++i) {
                    v4i t;
                    t.x = row[map_n[i * 4 + 0]];
                    t.y = row[map_n[i * 4 + 1]];
                    t.z = row[map_n[i * 4 + 2]];
                    t.w = row[map_n[i * 4 + 3]];
                    buf[q * 4 + i] = t;
                }
            }
        }

        const uint a0 = (uint)pack16(buf[0],  buf[1],  buf[2],  buf[3]);
        const uint a1 = (uint)pack16(buf[4],  buf[5],  buf[6],  buf[7]);
        const uint a2 = (uint)pack16(buf[8],  buf[9],  buf[10], buf[11]);
        const uint a3 = (uint)pack16(buf[12], buf[13], buf[14], buf[15]);

        uint2 st;                                  // 4 x u16, little-endian
        st.x = a0 | (a1 << 16);
        st.y = a2 | (a3 << 16);
        *reinterpret_cast<uint2*>(&addr_t[(size_t)s * NEUR + nb]) = st;
    }
}

// ---- Phase B: per neuron: counting-sort by line + double-buffered sweep ----
__global__ __launch_bounds__(THREADS, 4) void wisard_stream(
    const unsigned short* __restrict__ addr_t,   // [BATCH][NEUR]
    const int*   __restrict__ counts,
    const float* __restrict__ sums,
    float2*      __restrict__ contrib)           // [NEUR][BATCH]
{
    __shared__ uint hist[LINES];     // 16 KB
    __shared__ uint sorted[BATCH];   // 16 KB
    __shared__ uint ttot[THREADS];   //  1 KB
    __shared__ uint wsum[4];

    const int tid  = threadIdx.x;
    const int lane = tid & 63;
    const int w    = tid >> 6;
    // XCD swizzle: XCD x owns neurons [x*64, x*64+64) -> addr_t column
    // lines shared in that XCD's L2. 512 = 8*64 exact -> bijective.
    const int n = (blockIdx.x & 7) * 64 + (blockIdx.x >> 3);

    // 1. my 16 sample addresses (strided u16; XCD-L2 shared)
    uint a[16];
    #pragma unroll
    for (int j = 0; j < 16; ++j)
        a[j] = addr_t[(size_t)(j * THREADS + tid) * NEUR + n];

    // 2. histogram by table line (addr >> 4)
    #pragma unroll
    for (int j = 0; j < 16; ++j) hist[j * THREADS + tid] = 0u;
    __syncthreads();
    #pragma unroll
    for (int j = 0; j < 16; ++j) atomicAdd(&hist[a[j] >> 4], 1u);
    __syncthreads();

    // 3. exclusive scan of hist[4096]
    uint loc[16];
    uint run = 0;
    #pragma unroll
    for (int j = 0; j < 16; ++j) { loc[j] = run; run += hist[tid * 16 + j]; }
    ttot[tid] = run;
    __syncthreads();
    uint v = ttot[tid];
    #pragma unroll
    for (int off = 1; off < 64; off <<= 1) {
        const uint u = __shfl_up(v, off, 64);
        if (lane >= off) v += u;
    }
    if (lane == 63) wsum[w] = v;
    __syncthreads();
    uint woff = 0;
    for (int i = 0; i < w; ++i) woff += wsum[i];
    const uint excl = woff + v - run;
    #pragma unroll
    for (int j = 0; j < 16; ++j) hist[tid * 16 + j] = excl + loc[j];
    __syncthreads();

    // 4. scatter into line-sorted order: pack (addr<<12 | sample)
    #pragma unroll
    for (int j = 0; j < 16; ++j) {
        const uint pos = atomicAdd(&hist[a[j] >> 4], 1u);
        sorted[pos] = (a[j] << 12) | (uint)(j * THREADS + tid);
    }
    __syncthreads();
    // hist[L] is now the END offset of bucket L

    // 5. double-buffered full-table sweep; serve hits via DIRECT global
    //    stores (one store per sample, unconditional -> dense permutation
    //    of contrib[n][0..4095], L2 write-combines).
    const int* ci = counts + ((size_t)n << 16);
    const int* si = reinterpret_cast<const int*>(sums) + ((size_t)n << 16);
    float2*    cb = contrib + (size_t)n * BATCH;

    auto LD = [&](int L, v4i* c, v4i* s4) {
        const v4i* cp = reinterpret_cast<const v4i*>(ci + ((size_t)L << 4));
        const v4i* sp = reinterpret_cast<const v4i*>(si + ((size_t)L << 4));
        c[0] = cp[0]; c[1] = cp[1]; c[2] = cp[2]; c[3] = cp[3];
        s4[0] = sp[0]; s4[1] = sp[1]; s4[2] = sp[2]; s4[3] = sp[3];
    };
    auto SERVE = [&](int L, const v4i* c, const v4i* s4) {
        const uint beg = (L == 0) ? 0u : hist[L - 1];
        const uint end = hist[L];
        for (uint k = beg; k < end; ++k) {
            const uint pk = sorted[k];
            const int e  = (int)((pk >> 12) & 15u);
            const int sm = (int)(pk & 4095u);
            const int cv = sel16(c[0], c[1], c[2], c[3], e);
            const int sb = sel16(s4[0], s4[1], s4[2], s4[3], e);
            const bool tr = cv > 0;
            float2 o;
            o.x = tr ? __int_as_float(sb) : 0.0f;
            o.y = __int_as_float(tr ? cv : 0);
            cb[sm] = o;
        }
    };

    v4i cA[4], sA[4], cB[4], sB[4];
    LD(tid, cA, sA);
    #pragma unroll
    for (int j = 0; j < 16; j += 2) {
        LD((j + 1) * THREADS + tid, cB, sB);
        SERVE(j * THREADS + tid, cA, sA);
        if (j + 2 < 16) LD((j + 2) * THREADS + tid, cA, sA);
        SERVE((j + 1) * THREADS + tid, cB, sB);
    }
}

// ---- Phase C: reduce over neurons per sample (grid 256) --------------------
__global__ __launch_bounds__(THREADS) void wisard_final(
    const float2* __restrict__ contrib,
    float*        __restrict__ out)
{
    __shared__ float sr [4][16];
    __shared__ int   scn[4][16];
    const int tid  = threadIdx.x;
    const int lane = tid & 63;
    const int w    = tid >> 6;
    const int sloc = tid & 15;
    const int g    = tid >> 4;                 // 16 neuron groups
    const int s    = blockIdx.x * 16 + sloc;

    float r = 0.0f; int c = 0;
    #pragma unroll 8
    for (int i = 0; i < NEUR / 16; ++i) {
        const int n = g + i * 16;
        const float2 vv = contrib[(size_t)n * BATCH + s];
        r += vv.x;
        c += __float_as_int(vv.y);
    }
    r += __shfl_down(r, 32, 64); c += __shfl_down(c, 32, 64);
    r += __shfl_down(r, 16, 64); c += __shfl_down(c, 16, 64);
    if (lane < 16) { sr[w][lane] = r; scn[w][lane] = c; }
    __syncthreads();
    if (tid < 16) {
        r = sr[0][tid] + sr[1][tid] + sr[2][tid] + sr[3][tid];
        c = scn[0][tid] + scn[1][tid] + scn[2][tid] + scn[3][tid];
        out[blockIdx.x * 16 + tid] = (c > 0) ? (r / (float)c) : 0.0f;
    }
}

// ---- Fallback (R3): single-kernel direct gather, if workspace too small ----
__global__ __launch_bounds__(THREADS) void wisard_fallback(
    const int*   __restrict__ input,
    const int*   __restrict__ mapping,
    const int*   __restrict__ counts,
    const float* __restrict__ sums,
    float*       __restrict__ out)
{
    __shared__ float s_resp[2][THREADS / 64];
    __shared__ int   s_cnt [2][THREADS / 64];

    const int tid  = threadIdx.x;
    const int lane = tid & 63;
    const int wv   = tid >> 6;
    const int b0   = blockIdx.x * 2;

    int   cv[2][2];
    float sv[2][2];

    #pragma unroll
    for (int k = 0; k < 2; ++k) {
        const int n = tid + k * THREADS;
        const int* map_n = mapping + n * TUP;
        const int m0 = map_n[0];
        bool contig = ((m0 & 3) == 0);
        #pragma unroll
        for (int t = 1; t < TUP; ++t) contig &= (map_n[t] == m0 + t);
        #pragma unroll
        for (int s = 0; s < 2; ++s) {
            const int* row = input + (size_t)(b0 + s) * ENTRY;
            int a;
            if (contig) {
                const v4i* p = reinterpret_cast<const v4i*>(row + m0);
                a = pack16(__builtin_nontemporal_load(p),
                           __builtin_nontemporal_load(p + 1),
                           __builtin_nontemporal_load(p + 2),
                           __builtin_nontemporal_load(p + 3));
            } else {
                a = 0;
                #pragma unroll
                for (int t = 0; t < TUP; ++t) a = (a << 1) | (row[map_n[t]] & 1);
            }
            const size_t idx = ((size_t)n << 16) | (unsigned)a;
            cv[s][k] = counts[idx];
            sv[s][k] = sums[idx];
        }
    }

    float resp[2]; int cnt[2];
    #pragma unroll
    for (int s = 0; s < 2; ++s) {
        resp[s] = 0.0f; cnt[s] = 0;
        #pragma unroll
        for (int k = 0; k < 2; ++k) {
            const bool t = cv[s][k] > 0;
            resp[s] += t ? sv[s][k] : 0.0f;
            cnt [s] += t ? cv[s][k] : 0;
        }
    }
    #pragma unroll
    for (int s = 0; s < 2; ++s) {
        float r = resp[s]; int c = cnt[s];
        #pragma unroll
        for (int off = 32; off > 0; off >>= 1) {
            r += __shfl_down(r, off, 64);
            c += __shfl_down(c, off, 64);
        }
        if (lane == 0) { s_resp[s][wv] = r; s_cnt[s][wv] = c; }
    }
    __syncthreads();
    if (tid < 2) {
        float r = 0.0f; int c = 0;
        #pragma unroll
        for (int w = 0; w < THREADS / 64; ++w) { r += s_resp[tid][w]; c += s_cnt[tid][w]; }
        out[b0 + tid] = (c > 0) ? (r / (float)c) : 0.0f;
    }
}

extern "C" void kernel_launch(void* const* d_in, const int* in_sizes, int n_in,
                              void* d_out, int out_size, void* d_ws, size_t ws_size,
                              hipStream_t stream) {
    (void)in_sizes; (void)n_in; (void)out_size;
    const int*   input   = (const int*)d_in[0];
    const int*   mapping = (const int*)d_in[1];
    const int*   counts  = (const int*)d_in[2];
    const float* sums    = (const float*)d_in[3];
    float*       out     = (float*)d_out;

    const size_t contrib_bytes = (size_t)NEUR * BATCH * sizeof(float2);         // 16 MB
    const size_t addr_bytes    = (size_t)BATCH * NEUR * sizeof(unsigned short); //  4 MB

    if (ws_size < contrib_bytes + addr_bytes || d_ws == nullptr) {
        wisard_fallback<<<BATCH / 2, THREADS, 0, stream>>>(
            input, mapping, counts, sums, out);
        return;
    }

    float2*         contrib = (float2*)d_ws;
    unsigned short* addr_t  = (unsigned short*)((char*)d_ws + contrib_bytes);

    wisard_addr<<<BATCH / 4, THREADS, 0, stream>>>(input, mapping, addr_t);
    wisard_stream<<<NEUR, THREADS, 0, stream>>>(addr_t, counts, sums, contrib);
    wisard_final<<<BATCH / 16, THREADS, 0, stream>>>(contrib, out);
}

// Round 6
// 419.143 us; speedup vs baseline: 1.0482x; 1.0482x over previous
//
#include <hip/hip_runtime.h>

// RegressionWisard predict (centrality='mean')
//   input:  [B=4096, E=8192] int32 bits
//   map:    [E] permutation int32 (identity in the benchmark)
//   counts: [N=512, 65536] int32
//   sums:   [N=512, 65536] float32
//   out:    [B] float32 = nan_to_num(sum(s where c>0) / sum(c where c>0))
//
// R8: R7 regressed for two measured reasons: scattered global stores (WRITE
// 16->78MB) and grid-limited occupancy (512 blocks = 2/CU; launch_bounds
// can't add blocks). Fix: 512-thread stream blocks (16 waves/CU at the same
// grid), LDS acc + coalesced writeback restored, named-register double
// buffer + sched_barrier so the compiler can't sink the prefetch (R7's
// VGPR=52 showed it rewrote the pipeline). Addr kernel: flat 32-dwordx4
// burst per lane (512B contiguous), one uint4 store -> ~4KB/CU in flight.

constexpr int BATCH   = 4096;
constexpr int ENTRY   = 8192;
constexpr int TUP     = 16;
constexpr int NEUR    = ENTRY / TUP;    // 512
constexpr int LINES   = 4096;           // 16-entry (64B) lines per table
constexpr int TB      = 512;            // stream/addr block threads
constexpr int THREADS = 256;            // final/fallback block threads

typedef int v4i __attribute__((ext_vector_type(4)));
typedef unsigned int uint;

__device__ __forceinline__ int pack16(v4i b0, v4i b1, v4i b2, v4i b3) {
    // tuple bit 0 is the MSB of the address
    return ((b0.x & 1) << 15) | ((b0.y & 1) << 14)
         | ((b0.z & 1) << 13) | ((b0.w & 1) << 12)
         | ((b1.x & 1) << 11) | ((b1.y & 1) << 10)
         | ((b1.z & 1) <<  9) | ((b1.w & 1) <<  8)
         | ((b2.x & 1) <<  7) | ((b2.y & 1) <<  6)
         | ((b2.z & 1) <<  5) | ((b2.w & 1) <<  4)
         | ((b3.x & 1) <<  3) | ((b3.y & 1) <<  2)
         | ((b3.z & 1) <<  1) |  (b3.w & 1);
}

// 16-way register select via cndmask tree (static indices only; rule #20)
__device__ __forceinline__ int sel4(v4i v, int e01) {
    const int ab = (e01 & 1) ? v.y : v.x;
    const int cd = (e01 & 1) ? v.w : v.z;
    return (e01 & 2) ? cd : ab;
}
__device__ __forceinline__ int sel16(v4i v0, v4i v1, v4i v2, v4i v3, int e) {
    const int e2 = e & 3;
    const int a = sel4(v0, e2), b = sel4(v1, e2);
    const int c = sel4(v2, e2), d = sel4(v3, e2);
    const int ab = (e & 4) ? b : a;
    const int cd = (e & 4) ? d : c;
    return (e & 8) ? cd : ab;
}

// ---- Phase A: addr_t[s][n] --------------------------------------------------
// grid 512 x 512thr: wave = one sample; lane owns 8 neurons = 512B contiguous
// input; ALL 32 dwordx4 issued before any pack; one uint4 store per lane.
__global__ __launch_bounds__(TB, 2) void wisard_addr(
    const int* __restrict__ input,
    const int* __restrict__ mapping,
    unsigned short* __restrict__ addr_t)   // [BATCH][NEUR]
{
    const int lane = threadIdx.x & 63;
    const int w    = threadIdx.x >> 6;
    const int s    = blockIdx.x * 8 + w;
    const int* row = input + (size_t)s * ENTRY;
    const int nb   = lane * 8;             // my 8 neurons

    int  m0s[8];
    bool cg [8];
    #pragma unroll
    for (int q = 0; q < 8; ++q) {
        const int* map_n = mapping + (nb + q) * TUP;
        const int m0 = map_n[0];
        bool contig = ((m0 & 3) == 0);
        #pragma unroll
        for (int t = 1; t < TUP; ++t) contig &= (map_n[t] == m0 + t);
        m0s[q] = m0; cg[q] = contig;
    }

    // issue all 32 loads before any consumption (512B contiguous per lane)
    v4i buf[32];
    #pragma unroll
    for (int q = 0; q < 8; ++q) {
        if (cg[q]) {
            const v4i* p = reinterpret_cast<const v4i*>(row + m0s[q]);
            buf[q * 4 + 0] = __builtin_nontemporal_load(p);
            buf[q * 4 + 1] = __builtin_nontemporal_load(p + 1);
            buf[q * 4 + 2] = __builtin_nontemporal_load(p + 2);
            buf[q * 4 + 3] = __builtin_nontemporal_load(p + 3);
        } else {
            const int* map_n = mapping + (nb + q) * TUP;
            #pragma unroll
            for (int i = 0; i < 4; ++i) {
                v4i t;
                t.x = row[map_n[i * 4 + 0]];
                t.y = row[map_n[i * 4 + 1]];
                t.z = row[map_n[i * 4 + 2]];
                t.w = row[map_n[i * 4 + 3]];
                buf[q * 4 + i] = t;
            }
        }
    }

    uint a[8];
    #pragma unroll
    for (int q = 0; q < 8; ++q)
        a[q] = (uint)pack16(buf[q * 4], buf[q * 4 + 1], buf[q * 4 + 2], buf[q * 4 + 3]);

    uint4 st;                              // 8 x u16, little-endian
    st.x = a[0] | (a[1] << 16);
    st.y = a[2] | (a[3] << 16);
    st.z = a[4] | (a[5] << 16);
    st.w = a[6] | (a[7] << 16);
    *reinterpret_cast<uint4*>(&addr_t[(size_t)s * NEUR + nb]) = st;
}

// ---- Phase B: per neuron: counting-sort by line + double-buffered sweep ----
// 512 threads (8 waves): grid 512 -> 2 blocks/CU -> 16 waves/CU.
// LDS: hist 16K + sorted 16K + acc 32K + scratch ~2K = 66K -> 2 blocks/CU.
__global__ __launch_bounds__(TB, 4) void wisard_stream(
    const unsigned short* __restrict__ addr_t,   // [BATCH][NEUR]
    const int*   __restrict__ counts,
    const float* __restrict__ sums,
    float2*      __restrict__ contrib)           // [NEUR][BATCH]
{
    __shared__ uint   hist[LINES];     // 16 KB
    __shared__ uint   sorted[BATCH];   // 16 KB
    __shared__ float2 acc[BATCH];      // 32 KB
    __shared__ uint   ttot[TB];        //  2 KB
    __shared__ uint   wsum[TB / 64];

    const int tid  = threadIdx.x;
    const int lane = tid & 63;
    const int w    = tid >> 6;
    // XCD swizzle: XCD x owns neurons [x*64, x*64+64) -> addr_t column
    // lines shared in that XCD's L2. 512 = 8*64 exact -> bijective.
    const int n = (blockIdx.x & 7) * 64 + (blockIdx.x >> 3);

    // 1. my 8 sample addresses (strided u16; XCD-L2 shared)
    uint a[8];
    #pragma unroll
    for (int j = 0; j < 8; ++j)
        a[j] = addr_t[(size_t)(j * TB + tid) * NEUR + n];

    // 2. histogram by table line (addr >> 4)
    #pragma unroll
    for (int j = 0; j < 8; ++j) hist[j * TB + tid] = 0u;
    __syncthreads();
    #pragma unroll
    for (int j = 0; j < 8; ++j) atomicAdd(&hist[a[j] >> 4], 1u);
    __syncthreads();

    // 3. exclusive scan of hist[4096]: 8 serial buckets/thread + wave/block
    uint loc[8];
    uint run = 0;
    #pragma unroll
    for (int j = 0; j < 8; ++j) { loc[j] = run; run += hist[tid * 8 + j]; }
    ttot[tid] = run;
    __syncthreads();
    uint v = ttot[tid];
    #pragma unroll
    for (int off = 1; off < 64; off <<= 1) {
        const uint u = __shfl_up(v, off, 64);
        if (lane >= off) v += u;
    }
    if (lane == 63) wsum[w] = v;
    __syncthreads();
    uint woff = 0;
    #pragma unroll
    for (int i = 0; i < TB / 64; ++i) woff += (i < w) ? wsum[i] : 0u;
    const uint excl = woff + v - run;
    #pragma unroll
    for (int j = 0; j < 8; ++j) hist[tid * 8 + j] = excl + loc[j];
    __syncthreads();

    // 4. scatter into line-sorted order: pack (addr<<12 | sample)
    #pragma unroll
    for (int j = 0; j < 8; ++j) {
        const uint pos = atomicAdd(&hist[a[j] >> 4], 1u);
        sorted[pos] = (a[j] << 12) | (uint)(j * TB + tid);
    }
    __syncthreads();
    // hist[L] is now the END offset of bucket L. No acc zeroing needed:
    // every sample is served exactly once and written unconditionally.

    // 5. double-buffered full-table sweep (8 lines/thread), named registers.
    const int* ci = counts + ((size_t)n << 16);
    const int* si = reinterpret_cast<const int*>(sums) + ((size_t)n << 16);

#define LD(L, P) \
    { const v4i* cp_ = reinterpret_cast<const v4i*>(ci + ((size_t)(L) << 4)); \
      const v4i* sp_ = reinterpret_cast<const v4i*>(si + ((size_t)(L) << 4)); \
      c##P##0 = cp_[0]; c##P##1 = cp_[1]; c##P##2 = cp_[2]; c##P##3 = cp_[3]; \
      s##P##0 = sp_[0]; s##P##1 = sp_[1]; s##P##2 = sp_[2]; s##P##3 = sp_[3]; } \
    __builtin_amdgcn_sched_barrier(0);

#define SERVE(L, P) \
    { const uint beg_ = ((L) == 0) ? 0u : hist[(L) - 1]; \
      const uint end_ = hist[(L)]; \
      for (uint k_ = beg_; k_ < end_; ++k_) { \
        const uint pk_ = sorted[k_]; \
        const int e_  = (int)((pk_ >> 12) & 15u); \
        const int sm_ = (int)(pk_ & 4095u); \
        const int cv_ = sel16(c##P##0, c##P##1, c##P##2, c##P##3, e_); \
        const int sb_ = sel16(s##P##0, s##P##1, s##P##2, s##P##3, e_); \
        const bool tr_ = cv_ > 0; \
        float2 o_; \
        o_.x = tr_ ? __int_as_float(sb_) : 0.0f; \
        o_.y = __int_as_float(tr_ ? cv_ : 0); \
        acc[sm_] = o_; } }

    v4i cA0, cA1, cA2, cA3, sA0, sA1, sA2, sA3;
    v4i cB0, cB1, cB2, cB3, sB0, sB1, sB2, sB3;

    LD(tid, A)
    LD(TB + tid, B)
    SERVE(tid, A)
    LD(2 * TB + tid, A)
    SERVE(TB + tid, B)
    LD(3 * TB + tid, B)
    SERVE(2 * TB + tid, A)
    LD(4 * TB + tid, A)
    SERVE(3 * TB + tid, B)
    LD(5 * TB + tid, B)
    SERVE(4 * TB + tid, A)
    LD(6 * TB + tid, A)
    SERVE(5 * TB + tid, B)
    LD(7 * TB + tid, B)
    SERVE(6 * TB + tid, A)
    SERVE(7 * TB + tid, B)
#undef LD
#undef SERVE

    __syncthreads();

    // 6. coalesced writeback (512B per wave instruction)
    float2* cb = contrib + (size_t)n * BATCH;
    #pragma unroll
    for (int j = 0; j < 8; ++j) {
        const int sm = j * TB + tid;
        cb[sm] = acc[sm];
    }
}

// ---- Phase C: reduce over neurons per sample (grid 256) --------------------
__global__ __launch_bounds__(THREADS) void wisard_final(
    const float2* __restrict__ contrib,
    float*        __restrict__ out)
{
    __shared__ float sr [4][16];
    __shared__ int   scn[4][16];
    const int tid  = threadIdx.x;
    const int lane = tid & 63;
    const int w    = tid >> 6;
    const int sloc = tid & 15;
    const int g    = tid >> 4;                 // 16 neuron groups
    const int s    = blockIdx.x * 16 + sloc;

    float r = 0.0f; int c = 0;
    #pragma unroll 8
    for (int i = 0; i < NEUR / 16; ++i) {
        const int n = g + i * 16;
        const float2 vv = contrib[(size_t)n * BATCH + s];
        r += vv.x;
        c += __float_as_int(vv.y);
    }
    r += __shfl_down(r, 32, 64); c += __shfl_down(c, 32, 64);
    r += __shfl_down(r, 16, 64); c += __shfl_down(c, 16, 64);
    if (lane < 16) { sr[w][lane] = r; scn[w][lane] = c; }
    __syncthreads();
    if (tid < 16) {
        r = sr[0][tid] + sr[1][tid] + sr[2][tid] + sr[3][tid];
        c = scn[0][tid] + scn[1][tid] + scn[2][tid] + scn[3][tid];
        out[blockIdx.x * 16 + tid] = (c > 0) ? (r / (float)c) : 0.0f;
    }
}

// ---- Fallback (R3): single-kernel direct gather, if workspace too small ----
__global__ __launch_bounds__(THREADS) void wisard_fallback(
    const int*   __restrict__ input,
    const int*   __restrict__ mapping,
    const int*   __restrict__ counts,
    const float* __restrict__ sums,
    float*       __restrict__ out)
{
    __shared__ float s_resp[2][THREADS / 64];
    __shared__ int   s_cnt [2][THREADS / 64];

    const int tid  = threadIdx.x;
    const int lane = tid & 63;
    const int wv   = tid >> 6;
    const int b0   = blockIdx.x * 2;

    int   cv[2][2];
    float sv[2][2];

    #pragma unroll
    for (int k = 0; k < 2; ++k) {
        const int n = tid + k * THREADS;
        const int* map_n = mapping + n * TUP;
        const int m0 = map_n[0];
        bool contig = ((m0 & 3) == 0);
        #pragma unroll
        for (int t = 1; t < TUP; ++t) contig &= (map_n[t] == m0 + t);
        #pragma unroll
        for (int s = 0; s < 2; ++s) {
            const int* row = input + (size_t)(b0 + s) * ENTRY;
            int a;
            if (contig) {
                const v4i* p = reinterpret_cast<const v4i*>(row + m0);
                a = pack16(__builtin_nontemporal_load(p),
                           __builtin_nontemporal_load(p + 1),
                           __builtin_nontemporal_load(p + 2),
                           __builtin_nontemporal_load(p + 3));
            } else {
                a = 0;
                #pragma unroll
                for (int t = 0; t < TUP; ++t) a = (a << 1) | (row[map_n[t]] & 1);
            }
            const size_t idx = ((size_t)n << 16) | (unsigned)a;
            cv[s][k] = counts[idx];
            sv[s][k] = sums[idx];
        }
    }

    float resp[2]; int cnt[2];
    #pragma unroll
    for (int s = 0; s < 2; ++s) {
        resp[s] = 0.0f; cnt[s] = 0;
        #pragma unroll
        for (int k = 0; k < 2; ++k) {
            const bool t = cv[s][k] > 0;
            resp[s] += t ? sv[s][k] : 0.0f;
            cnt [s] += t ? cv[s][k] : 0;
        }
    }
    #pragma unroll
    for (int s = 0; s < 2; ++s) {
        float r = resp[s]; int c = cnt[s];
        #pragma unroll
        for (int off = 32; off > 0; off >>= 1) {
            r += __shfl_down(r, off, 64);
            c += __shfl_down(c, off, 64);
        }
        if (lane == 0) { s_resp[s][wv] = r; s_cnt[s][wv] = c; }
    }
    __syncthreads();
    if (tid < 2) {
        float r = 0.0f; int c = 0;
        #pragma unroll
        for (int w = 0; w < THREADS / 64; ++w) { r += s_resp[tid][w]; c += s_cnt[tid][w]; }
        out[b0 + tid] = (c > 0) ? (r / (float)c) : 0.0f;
    }
}

extern "C" void kernel_launch(void* const* d_in, const int* in_sizes, int n_in,
                              void* d_out, int out_size, void* d_ws, size_t ws_size,
                              hipStream_t stream) {
    (void)in_sizes; (void)n_in; (void)out_size;
    const int*   input   = (const int*)d_in[0];
    const int*   mapping = (const int*)d_in[1];
    const int*   counts  = (const int*)d_in[2];
    const float* sums    = (const float*)d_in[3];
    float*       out     = (float*)d_out;

    const size_t contrib_bytes = (size_t)NEUR * BATCH * sizeof(float2);         // 16 MB
    const size_t addr_bytes    = (size_t)BATCH * NEUR * sizeof(unsigned short); //  4 MB

    if (ws_size < contrib_bytes + addr_bytes || d_ws == nullptr) {
        wisard_fallback<<<BATCH / 2, THREADS, 0, stream>>>(
            input, mapping, counts, sums, out);
        return;
    }

    float2*         contrib = (float2*)d_ws;
    unsigned short* addr_t  = (unsigned short*)((char*)d_ws + contrib_bytes);

    wisard_addr<<<BATCH / 8, TB, 0, stream>>>(input, mapping, addr_t);
    wisard_stream<<<NEUR, TB, 0, stream>>>(addr_t, counts, sums, contrib);
    wisard_final<<<BATCH / 16, THREADS, 0, stream>>>(contrib, out);
}

// Round 7
// 377.606 us; speedup vs baseline: 1.1635x; 1.1100x over previous
//
#include <hip/hip_runtime.h>

// RegressionWisard predict (centrality='mean')
//   input:  [B=4096, E=8192] int32 bits
//   map:    [E] permutation int32 (identity in the benchmark)
//   counts: [N=512, 65536] int32
//   sums:   [N=512, 65536] float32
//   out:    [B] float32 = nan_to_num(sum(s where c>0) / sum(c where c>0))
//
// R9: R7/R8 proved VGPR-resident double-buffering gets rewritten by the
// compiler (VGPR=52 both times -> zero overlap). Switch the table sweep to
// ASYNC staging: global_load_lds holds bytes in flight in the VMEM queue
// (no VGPRs to steal), counted s_waitcnt vmcnt(8) keeps one 8KB phase
// always in flight per wave. Waves are autonomous (each thread serves only
// lines it staged) -> zero barriers in the sweep. Hits are served by
// entry-granular ds_reads (no sel16 trees). Addr kernel rebuilt flat
// grid-stride (32 waves/CU, 16 dwordx4 in flight, plain loads).

constexpr int BATCH   = 4096;
constexpr int ENTRY   = 8192;
constexpr int TUP     = 16;
constexpr int NEUR    = ENTRY / TUP;    // 512
constexpr int LINES   = 4096;           // 64B lines per neuron table
constexpr int THREADS = 256;

typedef int v4i __attribute__((ext_vector_type(4)));
typedef unsigned int uint;

__device__ __forceinline__ int pack16(v4i b0, v4i b1, v4i b2, v4i b3) {
    // tuple bit 0 is the MSB of the address
    return ((b0.x & 1) << 15) | ((b0.y & 1) << 14)
         | ((b0.z & 1) << 13) | ((b0.w & 1) << 12)
         | ((b1.x & 1) << 11) | ((b1.y & 1) << 10)
         | ((b1.z & 1) <<  9) | ((b1.w & 1) <<  8)
         | ((b2.x & 1) <<  7) | ((b2.y & 1) <<  6)
         | ((b2.z & 1) <<  5) | ((b2.w & 1) <<  4)
         | ((b3.x & 1) <<  3) | ((b3.y & 1) <<  2)
         | ((b3.z & 1) <<  1) |  (b3.w & 1);
}

// ---- Phase A: addr_t[word] for word = s*512+n ------------------------------
// Flat grid-stride: 2048 blocks x 256 thr x 4 words. Consecutive threads read
// consecutive 64B input chunks (identity mapping: offset = word*64B exactly).
// Plain (non-nt) loads. Stores: 4 consecutive u16 = one 8B store.
__global__ __launch_bounds__(THREADS) void wisard_addr(
    const int* __restrict__ input,
    const int* __restrict__ mapping,
    unsigned short* __restrict__ addr_t)   // [BATCH][NEUR] flattened
{
    const int t0 = (blockIdx.x * THREADS + threadIdx.x) * 4;   // first word

    v4i buf[16];
    #pragma unroll
    for (int q = 0; q < 4; ++q) {
        const int wd = t0 + q;
        const int s  = wd >> 9;
        const int n  = wd & 511;
        const v4i* mp = reinterpret_cast<const v4i*>(mapping + n * TUP);
        const v4i m0v = mp[0], m1v = mp[1], m2v = mp[2], m3v = mp[3];
        const int m0 = m0v.x;
        const bool contig = ((m0 & 3) == 0)
            && (m1v.x == m0 + 4) && (m2v.x == m0 + 8) && (m3v.x == m0 + 12)
            && (m0v.y == m0 + 1) && (m0v.z == m0 + 2) && (m0v.w == m0 + 3)
            && (m1v.y == m0 + 5) && (m1v.z == m0 + 6) && (m1v.w == m0 + 7)
            && (m2v.y == m0 + 9) && (m2v.z == m0 + 10) && (m2v.w == m0 + 11)
            && (m3v.y == m0 + 13) && (m3v.z == m0 + 14) && (m3v.w == m0 + 15);
        const int* row = input + (size_t)s * ENTRY;
        if (contig) {
            const v4i* p = reinterpret_cast<const v4i*>(row + m0);
            buf[q * 4 + 0] = p[0];
            buf[q * 4 + 1] = p[1];
            buf[q * 4 + 2] = p[2];
            buf[q * 4 + 3] = p[3];
        } else {
            const int* map_n = mapping + n * TUP;
            #pragma unroll
            for (int i = 0; i < 4; ++i) {
                v4i t;
                t.x = row[map_n[i * 4 + 0]];
                t.y = row[map_n[i * 4 + 1]];
                t.z = row[map_n[i * 4 + 2]];
                t.w = row[map_n[i * 4 + 3]];
                buf[q * 4 + i] = t;
            }
        }
    }

    ushort4 st;
    st.x = (unsigned short)pack16(buf[0],  buf[1],  buf[2],  buf[3]);
    st.y = (unsigned short)pack16(buf[4],  buf[5],  buf[6],  buf[7]);
    st.z = (unsigned short)pack16(buf[8],  buf[9],  buf[10], buf[11]);
    st.w = (unsigned short)pack16(buf[12], buf[13], buf[14], buf[15]);
    *reinterpret_cast<ushort4*>(&addr_t[t0]) = st;
}

// ---- Phase B: per neuron: counting-sort + async-staged table sweep ---------
__global__ __launch_bounds__(THREADS) void wisard_stream(
    const unsigned short* __restrict__ addr_t,   // [BATCH][NEUR]
    const int*   __restrict__ counts,
    const float* __restrict__ sums,
    float2*      __restrict__ contrib)           // [NEUR][BATCH]
{
    __shared__ uint           hist[LINES];            // 16 KB
    __shared__ unsigned short sorted[BATCH];          //  8 KB
    __shared__ float2         acc[BATCH];             // 32 KB
    __shared__ uint           ttot[THREADS];          //  1 KB
    __shared__ uint           wsum[4];
    __shared__ __align__(16) unsigned char stage[4][2][8192]; // 64 KB

    const int tid  = threadIdx.x;
    const int lane = tid & 63;
    const int w    = tid >> 6;
    // XCD swizzle: XCD x owns neurons [x*64, x*64+64) -> the addr_t column
    // bytes it needs (512 KB) stay in its L2. 512 = 8*64 exact -> bijective.
    const int n = (blockIdx.x & 7) * 64 + (blockIdx.x >> 3);

    // 1. my 16 sample addresses (u16 at 1KB stride; XCD-L2 resident)
    uint a[16];
    #pragma unroll
    for (int j = 0; j < 16; ++j)
        a[j] = addr_t[(size_t)(j * THREADS + tid) * NEUR + n];

    // 2. histogram by table line (addr >> 4)
    #pragma unroll
    for (int j = 0; j < 16; ++j) hist[j * THREADS + tid] = 0u;
    __syncthreads();
    #pragma unroll
    for (int j = 0; j < 16; ++j) atomicAdd(&hist[a[j] >> 4], 1u);
    __syncthreads();

    // 3. exclusive scan of hist[4096]: 16 serial buckets/thread + wave/block
    uint loc[16];
    uint run = 0;
    #pragma unroll
    for (int j = 0; j < 16; ++j) { loc[j] = run; run += hist[tid * 16 + j]; }
    ttot[tid] = run;
    __syncthreads();
    uint v = ttot[tid];
    #pragma unroll
    for (int off = 1; off < 64; off <<= 1) {
        const uint u = __shfl_up(v, off, 64);
        if (lane >= off) v += u;
    }
    if (lane == 63) wsum[w] = v;
    __syncthreads();
    uint woff = 0;
    #pragma unroll
    for (int i = 0; i < 4; ++i) woff += (i < w) ? wsum[i] : 0u;
    const uint excl = woff + v - run;
    #pragma unroll
    for (int j = 0; j < 16; ++j) hist[tid * 16 + j] = excl + loc[j];
    __syncthreads();

    // 4. scatter into line-sorted order: u16 = (entry<<12 | sample)
    #pragma unroll
    for (int j = 0; j < 16; ++j) {
        const uint pos = atomicAdd(&hist[a[j] >> 4], 1u);
        sorted[pos] = (unsigned short)(((a[j] & 15u) << 12) | (uint)(j * THREADS + tid));
    }
    __syncthreads();
    // hist[L] is now the END offset of bucket L. acc needs no zeroing: every
    // sample is served exactly once with an unconditional write.

    // 5. async-staged full-table sweep. Per phase j, wave w stages its 64
    //    lines (c: 4KB, s: 4KB) via 8x global_load_lds_dwordx4 (linear LDS
    //    dest = wave-uniform base + lane*16). Double-buffered per wave, NO
    //    barriers: thread (w,lane) serves exactly line j*256 + w*64 + lane,
    //    which its own wave staged. vmcnt(8) = previous phase landed while
    //    the next phase's 8 loads stay in flight (T4: never drain to 0).
    const char* cbase = reinterpret_cast<const char*>(counts + ((size_t)n << 16));
    const char* sbase = reinterpret_cast<const char*>(
                            reinterpret_cast<const int*>(sums) + ((size_t)n << 16));

#define STAGE(J, B) { \
    const uint base_ = (uint)(((J) * 256 + w * 64) * 64); \
    _Pragma("unroll") \
    for (int i_ = 0; i_ < 4; ++i_) { \
        __builtin_amdgcn_global_load_lds( \
            (const __attribute__((address_space(1))) uint*)(cbase + base_ + i_ * 1024 + lane * 16), \
            (__attribute__((address_space(3))) uint*)&stage[w][(B)][i_ * 1024], 16, 0, 0); \
        __builtin_amdgcn_global_load_lds( \
            (const __attribute__((address_space(1))) uint*)(sbase + base_ + i_ * 1024 + lane * 16), \
            (__attribute__((address_space(3))) uint*)&stage[w][(B)][4096 + i_ * 1024], 16, 0, 0); \
    } }

#define SERVE(J, B) { \
    const int L_ = (J) * 256 + tid; \
    const uint beg_ = (L_ == 0) ? 0u : hist[L_ - 1]; \
    const uint end_ = hist[L_]; \
    const unsigned char* cs_ = &stage[w][(B)][(uint)lane * 64]; \
    const unsigned char* ss_ = &stage[w][(B)][4096 + (uint)lane * 64]; \
    for (uint k_ = beg_; k_ < end_; ++k_) { \
        const uint pk_ = sorted[k_]; \
        const int e_  = (int)(pk_ >> 12); \
        const int sm_ = (int)(pk_ & 4095u); \
        const int   cv_ = *reinterpret_cast<const int*>(cs_ + e_ * 4); \
        const float sv_ = *reinterpret_cast<const float*>(ss_ + e_ * 4); \
        const bool tr_ = cv_ > 0; \
        float2 o_; \
        o_.x = tr_ ? sv_ : 0.0f; \
        o_.y = __int_as_float(tr_ ? cv_ : 0); \
        acc[sm_] = o_; \
    } }

    STAGE(0, 0)
    #pragma unroll 1
    for (int j = 0; j < 15; ++j) {
        STAGE(j + 1, (j + 1) & 1)
        asm volatile("s_waitcnt vmcnt(8)" ::: "memory");
        SERVE(j, j & 1)
    }
    asm volatile("s_waitcnt vmcnt(0)" ::: "memory");
    SERVE(15, 1)
#undef STAGE
#undef SERVE

    __syncthreads();

    // 6. coalesced writeback (2KB per wave instruction)
    float2* cb = contrib + (size_t)n * BATCH;
    #pragma unroll
    for (int j = 0; j < 16; ++j) {
        const int sm = j * THREADS + tid;
        cb[sm] = acc[sm];
    }
}

// ---- Phase C: reduce over neurons per sample (grid 256) --------------------
__global__ __launch_bounds__(THREADS) void wisard_final(
    const float2* __restrict__ contrib,
    float*        __restrict__ out)
{
    __shared__ float sr [4][16];
    __shared__ int   scn[4][16];
    const int tid  = threadIdx.x;
    const int lane = tid & 63;
    const int w    = tid >> 6;
    const int sloc = tid & 15;
    const int g    = tid >> 4;                 // 16 neuron groups
    const int s    = blockIdx.x * 16 + sloc;

    float r = 0.0f; int c = 0;
    #pragma unroll 8
    for (int i = 0; i < NEUR / 16; ++i) {
        const int n = g + i * 16;
        const float2 vv = contrib[(size_t)n * BATCH + s];
        r += vv.x;
        c += __float_as_int(vv.y);
    }
    r += __shfl_down(r, 32, 64); c += __shfl_down(c, 32, 64);
    r += __shfl_down(r, 16, 64); c += __shfl_down(c, 16, 64);
    if (lane < 16) { sr[w][lane] = r; scn[w][lane] = c; }
    __syncthreads();
    if (tid < 16) {
        r = sr[0][tid] + sr[1][tid] + sr[2][tid] + sr[3][tid];
        c = scn[0][tid] + scn[1][tid] + scn[2][tid] + scn[3][tid];
        out[blockIdx.x * 16 + tid] = (c > 0) ? (r / (float)c) : 0.0f;
    }
}

// ---- Fallback (R3): single-kernel direct gather, if workspace too small ----
__global__ __launch_bounds__(THREADS) void wisard_fallback(
    const int*   __restrict__ input,
    const int*   __restrict__ mapping,
    const int*   __restrict__ counts,
    const float* __restrict__ sums,
    float*       __restrict__ out)
{
    __shared__ float s_resp[2][THREADS / 64];
    __shared__ int   s_cnt [2][THREADS / 64];

    const int tid  = threadIdx.x;
    const int lane = tid & 63;
    const int wv   = tid >> 6;
    const int b0   = blockIdx.x * 2;

    int   cv[2][2];
    float sv[2][2];

    #pragma unroll
    for (int k = 0; k < 2; ++k) {
        const int n = tid + k * THREADS;
        const int* map_n = mapping + n * TUP;
        const int m0 = map_n[0];
        bool contig = ((m0 & 3) == 0);
        #pragma unroll
        for (int t = 1; t < TUP; ++t) contig &= (map_n[t] == m0 + t);
        #pragma unroll
        for (int s = 0; s < 2; ++s) {
            const int* row = input + (size_t)(b0 + s) * ENTRY;
            int a;
            if (contig) {
                const v4i* p = reinterpret_cast<const v4i*>(row + m0);
                a = pack16(p[0], p[1], p[2], p[3]);
            } else {
                a = 0;
                #pragma unroll
                for (int t = 0; t < TUP; ++t) a = (a << 1) | (row[map_n[t]] & 1);
            }
            const size_t idx = ((size_t)n << 16) | (unsigned)a;
            cv[s][k] = counts[idx];
            sv[s][k] = sums[idx];
        }
    }

    float resp[2]; int cnt[2];
    #pragma unroll
    for (int s = 0; s < 2; ++s) {
        resp[s] = 0.0f; cnt[s] = 0;
        #pragma unroll
        for (int k = 0; k < 2; ++k) {
            const bool t = cv[s][k] > 0;
            resp[s] += t ? sv[s][k] : 0.0f;
            cnt [s] += t ? cv[s][k] : 0;
        }
    }
    #pragma unroll
    for (int s = 0; s < 2; ++s) {
        float r = resp[s]; int c = cnt[s];
        #pragma unroll
        for (int off = 32; off > 0; off >>= 1) {
            r += __shfl_down(r, off, 64);
            c += __shfl_down(c, off, 64);
        }
        if (lane == 0) { s_resp[s][wv] = r; s_cnt[s][wv] = c; }
    }
    __syncthreads();
    if (tid < 2) {
        float r = 0.0f; int c = 0;
        #pragma unroll
        for (int w = 0; w < THREADS / 64; ++w) { r += s_resp[tid][w]; c += s_cnt[tid][w]; }
        out[b0 + tid] = (c > 0) ? (r / (float)c) : 0.0f;
    }
}

extern "C" void kernel_launch(void* const* d_in, const int* in_sizes, int n_in,
                              void* d_out, int out_size, void* d_ws, size_t ws_size,
                              hipStream_t stream) {
    (void)in_sizes; (void)n_in; (void)out_size;
    const int*   input   = (const int*)d_in[0];
    const int*   mapping = (const int*)d_in[1];
    const int*   counts  = (const int*)d_in[2];
    const float* sums    = (const float*)d_in[3];
    float*       out     = (float*)d_out;

    const size_t contrib_bytes = (size_t)NEUR * BATCH * sizeof(float2);         // 16 MB
    const size_t addr_bytes    = (size_t)BATCH * NEUR * sizeof(unsigned short); //  4 MB

    if (ws_size < contrib_bytes + addr_bytes || d_ws == nullptr) {
        wisard_fallback<<<BATCH / 2, THREADS, 0, stream>>>(
            input, mapping, counts, sums, out);
        return;
    }

    float2*         contrib = (float2*)d_ws;
    unsigned short* addr_t  = (unsigned short*)((char*)d_ws + contrib_bytes);

    wisard_addr<<<(BATCH * NEUR) / (THREADS * 4), THREADS, 0, stream>>>(
        input, mapping, addr_t);
    wisard_stream<<<NEUR, THREADS, 0, stream>>>(addr_t, counts, sums, contrib);
    wisard_final<<<BATCH / 16, THREADS, 0, stream>>>(contrib, out);
}